// Round 1
// baseline (250.280 us; speedup 1.0000x reference)
//
#include <hip/hip_runtime.h>
#include <hip/hip_bf16.h>

// Problem constants (from reference)
constexpr int BATCH = 4096;   // N
constexpr int NCLS  = 751;    // classes
constexpr int FDIM  = 2048;   // D
constexpr int TILE  = 128;    // C-tile (square)
constexpr int BK    = 32;     // K-step (one mfma_16x16x32 per step)
constexpr float MARGIN = 0.5f;

typedef __attribute__((ext_vector_type(8))) short bf16x8;  // 8 bf16 = 4 VGPRs
typedef __attribute__((ext_vector_type(4))) float f32x4;

// ---------------- helpers ----------------
__device__ __forceinline__ float wave_sum(float v) {
#pragma unroll
  for (int m = 32; m >= 1; m >>= 1) v += __shfl_xor(v, m, 64);
  return v;
}

__device__ __forceinline__ unsigned short bf_bits(float x) {
  unsigned u = __float_as_uint(x);
  u += 0x7FFFu + ((u >> 16) & 1u);   // RNE to bf16
  return (unsigned short)(u >> 16);
}

__device__ __forceinline__ void gld_lds16(const void* g, void* l) {
  __builtin_amdgcn_global_load_lds(
      (const __attribute__((address_space(1))) void*)g,
      (__attribute__((address_space(3))) void*)l, 16, 0, 0);
}

// ---------------- kernel 1: fp32->bf16 convert + row sum-of-squares + ws init ----
__global__ void convert_init_kernel(const float* __restrict__ feat,
                                    unsigned short* __restrict__ fb,
                                    float* __restrict__ sq,
                                    int* __restrict__ an, int* __restrict__ ap,
                                    float* __restrict__ xsum) {
  const int row = blockIdx.x;
  const int tid = threadIdx.x;
  const float4* src = (const float4*)(feat + (size_t)row * FDIM);
  ushort4* dst = (ushort4*)(fb + (size_t)row * FDIM);
  float s = 0.f;
#pragma unroll
  for (int it = 0; it < 2; ++it) {
    const int idx = it * 256 + tid;          // 512 float4 per row
    float4 v = src[idx];
    s += v.x * v.x + v.y * v.y + v.z * v.z + v.w * v.w;
    ushort4 o;
    o.x = bf_bits(v.x); o.y = bf_bits(v.y); o.z = bf_bits(v.z); o.w = bf_bits(v.w);
    dst[idx] = o;
  }
  s = wave_sum(s);
  __shared__ float ss[4];
  if ((tid & 63) == 0) ss[tid >> 6] = s;
  __syncthreads();
  if (tid == 0) {
    sq[row] = ss[0] + ss[1] + ss[2] + ss[3];
    an[row] = 0x7F000000;   // large positive float bits (min identity)
    ap[row] = 0;            // 0.0f bits (max identity; dist >= 0)
    if (row == 0) xsum[0] = 0.f;
  }
}

// ---------------- kernel 2: cross-entropy (one block per row) ----------------
__global__ void xent_kernel(const float* __restrict__ logits,
                            const int* __restrict__ tgt,
                            float* __restrict__ xsum) {
  const int row = blockIdx.x;
  const int tid = threadIdx.x;
  const float* lg = logits + (size_t)row * NCLS;
  float m = -1e30f;
  for (int j = tid; j < NCLS; j += 256) m = fmaxf(m, lg[j]);
#pragma unroll
  for (int k = 32; k >= 1; k >>= 1) m = fmaxf(m, __shfl_xor(m, k, 64));
  __shared__ float sm[4];
  if ((tid & 63) == 0) sm[tid >> 6] = m;
  __syncthreads();
  m = fmaxf(fmaxf(sm[0], sm[1]), fmaxf(sm[2], sm[3]));

  float se = 0.f;
  for (int j = tid; j < NCLS; j += 256) se += __expf(lg[j] - m);
  se = wave_sum(se);
  __shared__ float ss[4];
  if ((tid & 63) == 0) ss[tid >> 6] = se;
  __syncthreads();
  if (tid == 0) {
    const float tot = ss[0] + ss[1] + ss[2] + ss[3];
    const float lp = lg[tgt[row]] - m - logf(tot);
    atomicAdd(xsum, -lp);   // sum of -logp[i, t_i]
  }
}

// ---------------- kernel 3: bf16 MFMA Gram + fused batch-hard mining ----------
// C-tile 128x128, 4 waves in 2x2, each wave 4x4 grid of 16x16x32 MFMA.
__global__ __launch_bounds__(256) void gemm_mine_kernel(
    const unsigned short* __restrict__ fb, const float* __restrict__ sq,
    int* __restrict__ an, int* __restrict__ ap) {
  __shared__ __align__(16) unsigned short As[TILE * BK];  // 8 KB, row-major [128][32]
  __shared__ __align__(16) unsigned short Bs[TILE * BK];
  const int bi = blockIdx.y, bj = blockIdx.x;
  const int i0 = bi * TILE, j0 = bj * TILE;
  const int tid = threadIdx.x;
  const int wave = tid >> 6, lane = tid & 63;
  const int wm = wave >> 1, wn = wave & 1;        // 2x2 wave grid
  const int quad = lane >> 4, lr = lane & 15;

  f32x4 acc[4][4];
  const f32x4 zero = {0.f, 0.f, 0.f, 0.f};
#pragma unroll
  for (int mi = 0; mi < 4; ++mi)
#pragma unroll
    for (int ni = 0; ni < 4; ++ni) acc[mi][ni] = zero;

  // staging map: thread t loads 8 contiguous bf16 -> LDS offset t*16B
  const int r = tid >> 2;          // 0..63
  const int c = (tid & 3) * 8;     // 0,8,16,24
  const unsigned short* gA = fb + (size_t)(i0 + r) * FDIM + c;
  const unsigned short* gB = fb + (size_t)(j0 + r) * FDIM + c;
  unsigned short* lA = &As[r * BK + c];
  unsigned short* lB = &Bs[r * BK + c];

  for (int k0 = 0; k0 < FDIM; k0 += BK) {
    __syncthreads();               // previous iter's LDS reads done
    gld_lds16(gA + k0, lA);
    gld_lds16(gA + k0 + (size_t)64 * FDIM, lA + 64 * BK);
    gld_lds16(gB + k0, lB);
    gld_lds16(gB + k0 + (size_t)64 * FDIM, lB + 64 * BK);
    __syncthreads();               // staging visible (vmcnt drained by barrier)

    bf16x8 a[4], b[4];
#pragma unroll
    for (int mi = 0; mi < 4; ++mi)
      a[mi] = *(const bf16x8*)&As[(wm * 64 + mi * 16 + lr) * BK + quad * 8];
#pragma unroll
    for (int ni = 0; ni < 4; ++ni)
      b[ni] = *(const bf16x8*)&Bs[(wn * 64 + ni * 16 + lr) * BK + quad * 8];
#pragma unroll
    for (int mi = 0; mi < 4; ++mi)
#pragma unroll
      for (int ni = 0; ni < 4; ++ni)
        acc[mi][ni] = __builtin_amdgcn_mfma_f32_16x16x32_bf16(
            a[mi], b[ni], acc[mi][ni], 0, 0, 0);
  }

  // ---- epilogue: dist + batch-hard mining, dist matrix never materialized ----
  // D layout (16x16x32): col = lane&15 (j), row = quad*4 + reg (i)
  const bool diag = (bi == bj);    // only diagonal blocks contain same-group cols
  float sqj[4];
#pragma unroll
  for (int ni = 0; ni < 4; ++ni) sqj[ni] = sq[j0 + wn * 64 + ni * 16 + lr];

  float rmin[4][4], rmax[4][4];
#pragma unroll
  for (int mi = 0; mi < 4; ++mi)
#pragma unroll
    for (int rg = 0; rg < 4; ++rg) { rmin[mi][rg] = 1e30f; rmax[mi][rg] = 0.f; }

#pragma unroll
  for (int mi = 0; mi < 4; ++mi) {
#pragma unroll
    for (int rg = 0; rg < 4; ++rg) {
      const int i = i0 + wm * 64 + mi * 16 + quad * 4 + rg;
      const float si = sq[i];
      const int gi = i >> 2;       // group id (targets = idx//4)
#pragma unroll
      for (int ni = 0; ni < 4; ++ni) {
        const int j = j0 + wn * 64 + ni * 16 + lr;
        const float d2 = si + sqj[ni] - 2.f * acc[mi][ni][rg];
        const float dist = sqrtf(fmaxf(d2, 1e-12f));
        if ((j >> 2) == gi) rmax[mi][rg] = fmaxf(rmax[mi][rg], dist);
        else                rmin[mi][rg] = fminf(rmin[mi][rg], dist);
      }
    }
  }

  // reduce across the 16 lanes (lr) that share each output row
#pragma unroll
  for (int m = 1; m < 16; m <<= 1) {
#pragma unroll
    for (int mi = 0; mi < 4; ++mi)
#pragma unroll
      for (int rg = 0; rg < 4; ++rg) {
        rmin[mi][rg] = fminf(rmin[mi][rg], __shfl_xor(rmin[mi][rg], m, 64));
        if (diag)
          rmax[mi][rg] = fmaxf(rmax[mi][rg], __shfl_xor(rmax[mi][rg], m, 64));
      }
  }
  if (lr == 0) {
#pragma unroll
    for (int mi = 0; mi < 4; ++mi)
#pragma unroll
      for (int rg = 0; rg < 4; ++rg) {
        const int i = i0 + wm * 64 + mi * 16 + quad * 4 + rg;
        // dist >= 0 -> positive float bits order like ints
        atomicMin(&an[i], __float_as_int(rmin[mi][rg]));
        if (diag) atomicMax(&ap[i], __float_as_int(rmax[mi][rg]));
      }
  }
}

// ---------------- kernel 4: final combine ----------------
__global__ void final_kernel(const int* __restrict__ an, const int* __restrict__ ap,
                             const float* __restrict__ xsum, float* __restrict__ out) {
  const int tid = threadIdx.x;
  float s = 0.f;
  for (int i = tid; i < BATCH; i += 256) {
    const float a = __int_as_float(ap[i]);
    const float b = __int_as_float(an[i]);
    s += fmaxf(a - b + MARGIN, 0.f);
  }
  s = wave_sum(s);
  __shared__ float ss[4];
  if ((tid & 63) == 0) ss[tid >> 6] = s;
  __syncthreads();
  if (tid == 0) {
    const float trip = (ss[0] + ss[1] + ss[2] + ss[3]) / (float)BATCH;
    out[0] = xsum[0] / (float)BATCH + trip;  // ALPHA=BETA=1
  }
}

// ---------------- launch ----------------
extern "C" void kernel_launch(void* const* d_in, const int* in_sizes, int n_in,
                              void* d_out, int out_size, void* d_ws, size_t ws_size,
                              hipStream_t stream) {
  const float* logits = (const float*)d_in[0];
  const float* feat   = (const float*)d_in[1];
  const int*   tgt    = (const int*)d_in[2];
  float* out = (float*)d_out;

  // ws layout: bf16 feat copy (16 MB) | sq | an | ap | xsum
  char* ws = (char*)d_ws;
  unsigned short* fb = (unsigned short*)ws;
  size_t off = (size_t)BATCH * FDIM * sizeof(unsigned short);
  float* sq  = (float*)(ws + off);  off += BATCH * sizeof(float);
  int*   an  = (int*)(ws + off);    off += BATCH * sizeof(int);
  int*   ap  = (int*)(ws + off);    off += BATCH * sizeof(int);
  float* xsum = (float*)(ws + off);

  convert_init_kernel<<<BATCH, 256, 0, stream>>>(feat, fb, sq, an, ap, xsum);
  xent_kernel<<<BATCH, 256, 0, stream>>>(logits, tgt, xsum);
  gemm_mine_kernel<<<dim3(BATCH / TILE, BATCH / TILE), 256, 0, stream>>>(fb, sq, an, ap);
  final_kernel<<<1, 256, 0, stream>>>(an, ap, xsum, out);
}

// Round 2
// 181.659 us; speedup vs baseline: 1.3777x; 1.3777x over previous
//
#include <hip/hip_runtime.h>
#include <hip/hip_bf16.h>

// Problem constants (from reference)
constexpr int BATCH = 4096;   // N
constexpr int NCLS  = 751;    // classes
constexpr int FDIM  = 2048;   // D
constexpr int TILE  = 128;    // C-tile (square)
constexpr int BK    = 32;     // K-step (one mfma_16x16x32 per step)
constexpr float MARGIN = 0.5f;

typedef __attribute__((ext_vector_type(8))) short bf16x8;  // 8 bf16 = 4 VGPRs
typedef __attribute__((ext_vector_type(4))) float f32x4;

// ---------------- helpers ----------------
__device__ __forceinline__ float wave_sum(float v) {
#pragma unroll
  for (int m = 32; m >= 1; m >>= 1) v += __shfl_xor(v, m, 64);
  return v;
}

__device__ __forceinline__ unsigned short bf_bits(float x) {
  unsigned u = __float_as_uint(x);
  u += 0x7FFFu + ((u >> 16) & 1u);   // RNE to bf16
  return (unsigned short)(u >> 16);
}

__device__ __forceinline__ void gld_lds16(const void* g, void* l) {
  __builtin_amdgcn_global_load_lds(
      (const __attribute__((address_space(1))) void*)g,
      (__attribute__((address_space(3))) void*)l, 16, 0, 0);
}

// ---------------- kernel 1: fp32->bf16 convert + row sum-of-squares + ws init ----
__global__ void convert_init_kernel(const float* __restrict__ feat,
                                    unsigned short* __restrict__ fb,
                                    float* __restrict__ sq,
                                    int* __restrict__ an, int* __restrict__ ap) {
  const int row = blockIdx.x;
  const int tid = threadIdx.x;
  const float4* src = (const float4*)(feat + (size_t)row * FDIM);
  ushort4* dst = (ushort4*)(fb + (size_t)row * FDIM);
  float s = 0.f;
#pragma unroll
  for (int it = 0; it < 2; ++it) {
    const int idx = it * 256 + tid;          // 512 float4 per row
    float4 v = src[idx];
    s += v.x * v.x + v.y * v.y + v.z * v.z + v.w * v.w;
    ushort4 o;
    o.x = bf_bits(v.x); o.y = bf_bits(v.y); o.z = bf_bits(v.z); o.w = bf_bits(v.w);
    dst[idx] = o;
  }
  s = wave_sum(s);
  __shared__ float ss[4];
  if ((tid & 63) == 0) ss[tid >> 6] = s;
  __syncthreads();
  if (tid == 0) {
    sq[row] = ss[0] + ss[1] + ss[2] + ss[3];
    an[row] = 0x7F000000;   // large positive float bits (min identity)
    ap[row] = 0;            // 0.0f bits (max identity; dist >= 0)
  }
}

// ---------------- kernel 2: cross-entropy per row (NO shared atomic) ----------
__global__ void xent_kernel(const float* __restrict__ logits,
                            const int* __restrict__ tgt,
                            float* __restrict__ xloss) {
  const int row = blockIdx.x;
  const int tid = threadIdx.x;
  const float* lg = logits + (size_t)row * NCLS;
  float m = -1e30f;
  for (int j = tid; j < NCLS; j += 256) m = fmaxf(m, lg[j]);
#pragma unroll
  for (int k = 32; k >= 1; k >>= 1) m = fmaxf(m, __shfl_xor(m, k, 64));
  __shared__ float sm[4];
  if ((tid & 63) == 0) sm[tid >> 6] = m;
  __syncthreads();
  m = fmaxf(fmaxf(sm[0], sm[1]), fmaxf(sm[2], sm[3]));

  float se = 0.f;
  for (int j = tid; j < NCLS; j += 256) se += __expf(lg[j] - m);
  se = wave_sum(se);
  __shared__ float ss[4];
  if ((tid & 63) == 0) ss[tid >> 6] = se;
  __syncthreads();
  if (tid == 0) {
    const float tot = ss[0] + ss[1] + ss[2] + ss[3];
    xloss[row] = -(lg[tgt[row]] - m - logf(tot));   // plain store, no contention
  }
}

// ---------------- kernel 3: symmetric bf16 MFMA Gram + fused batch-hard mining
// Lower triangle only: 528 blocks. Off-diag tiles mine rows AND columns
// (symmetry); diagonal tiles are symmetric so row mining covers them.
__global__ __launch_bounds__(256) void gemm_mine_kernel(
    const unsigned short* __restrict__ fb, const float* __restrict__ sq,
    int* __restrict__ an, int* __restrict__ ap) {
  __shared__ __align__(16) unsigned short As[TILE * BK];  // 8 KB [128][32]
  __shared__ __align__(16) unsigned short Bs[TILE * BK];

  // decode lower-triangle index: k -> (bi, bj), bi >= bj
  const int k = blockIdx.x;
  int bi = (int)((sqrtf(8.f * (float)k + 1.f) - 1.f) * 0.5f);
  while ((bi + 1) * (bi + 2) / 2 <= k) ++bi;
  while (bi * (bi + 1) / 2 > k) --bi;
  const int bj = k - bi * (bi + 1) / 2;
  const bool diag = (bi == bj);

  const int i0 = bi * TILE, j0 = bj * TILE;
  const int tid = threadIdx.x;
  const int wave = tid >> 6, lane = tid & 63;
  const int wm = wave >> 1, wn = wave & 1;        // 2x2 wave grid
  const int quad = lane >> 4, lr = lane & 15;

  f32x4 acc[4][4];
  const f32x4 zero = {0.f, 0.f, 0.f, 0.f};
#pragma unroll
  for (int mi = 0; mi < 4; ++mi)
#pragma unroll
    for (int ni = 0; ni < 4; ++ni) acc[mi][ni] = zero;

  // staging map: thread t loads 8 contiguous bf16 -> LDS offset t*16B
  const int r = tid >> 2;          // 0..63
  const int c = (tid & 3) * 8;     // 0,8,16,24
  const unsigned short* gA = fb + (size_t)(i0 + r) * FDIM + c;
  const unsigned short* gB = fb + (size_t)(j0 + r) * FDIM + c;
  unsigned short* lA = &As[r * BK + c];
  unsigned short* lB = &Bs[r * BK + c];
  const unsigned short* Bsrc = diag ? As : Bs;   // diag: B-frags come from As

  for (int k0 = 0; k0 < FDIM; k0 += BK) {
    __syncthreads();               // previous iter's LDS reads done
    gld_lds16(gA + k0, lA);
    gld_lds16(gA + k0 + (size_t)64 * FDIM, lA + 64 * BK);
    if (!diag) {
      gld_lds16(gB + k0, lB);
      gld_lds16(gB + k0 + (size_t)64 * FDIM, lB + 64 * BK);
    }
    __syncthreads();               // staging visible

    bf16x8 a[4], b[4];
#pragma unroll
    for (int mi = 0; mi < 4; ++mi)
      a[mi] = *(const bf16x8*)&As[(wm * 64 + mi * 16 + lr) * BK + quad * 8];
#pragma unroll
    for (int ni = 0; ni < 4; ++ni)
      b[ni] = *(const bf16x8*)&Bsrc[(wn * 64 + ni * 16 + lr) * BK + quad * 8];
#pragma unroll
    for (int mi = 0; mi < 4; ++mi)
#pragma unroll
      for (int ni = 0; ni < 4; ++ni)
        acc[mi][ni] = __builtin_amdgcn_mfma_f32_16x16x32_bf16(
            a[mi], b[ni], acc[mi][ni], 0, 0, 0);
  }

  // ---- epilogue: D layout col = lane&15 (j), row = quad*4 + reg (i) ----
  float sqj[4];
#pragma unroll
  for (int ni = 0; ni < 4; ++ni) sqj[ni] = sq[j0 + wn * 64 + ni * 16 + lr];

  if (diag) {
    // same-group pairs live only here; tile symmetric -> row mining suffices
    float rmin[4][4], rmax[4][4];
#pragma unroll
    for (int mi = 0; mi < 4; ++mi)
#pragma unroll
      for (int rg = 0; rg < 4; ++rg) { rmin[mi][rg] = 1e30f; rmax[mi][rg] = 0.f; }
#pragma unroll
    for (int mi = 0; mi < 4; ++mi) {
#pragma unroll
      for (int rg = 0; rg < 4; ++rg) {
        const int i = i0 + wm * 64 + mi * 16 + quad * 4 + rg;
        const float si = sq[i];
        const int gi = i >> 2;       // targets = idx // 4
#pragma unroll
        for (int ni = 0; ni < 4; ++ni) {
          const int j = j0 + wn * 64 + ni * 16 + lr;
          const float d2 = si + sqj[ni] - 2.f * acc[mi][ni][rg];
          const float dist = sqrtf(fmaxf(d2, 1e-12f));
          if ((j >> 2) == gi) rmax[mi][rg] = fmaxf(rmax[mi][rg], dist);
          else                rmin[mi][rg] = fminf(rmin[mi][rg], dist);
        }
      }
    }
#pragma unroll
    for (int m = 1; m < 16; m <<= 1)
#pragma unroll
      for (int mi = 0; mi < 4; ++mi)
#pragma unroll
        for (int rg = 0; rg < 4; ++rg) {
          rmin[mi][rg] = fminf(rmin[mi][rg], __shfl_xor(rmin[mi][rg], m, 64));
          rmax[mi][rg] = fmaxf(rmax[mi][rg], __shfl_xor(rmax[mi][rg], m, 64));
        }
    if (lr == 0) {
#pragma unroll
      for (int mi = 0; mi < 4; ++mi)
#pragma unroll
        for (int rg = 0; rg < 4; ++rg) {
          const int i = i0 + wm * 64 + mi * 16 + quad * 4 + rg;
          atomicMin(&an[i], __float_as_int(rmin[mi][rg]));
          atomicMax(&ap[i], __float_as_int(rmax[mi][rg]));
        }
    }
  } else {
    // all cross-group: row-min -> an[i], col-min (symmetry) -> an[j]
    float rmin[4][4];
    float cmin[4] = {1e30f, 1e30f, 1e30f, 1e30f};
#pragma unroll
    for (int mi = 0; mi < 4; ++mi)
#pragma unroll
      for (int rg = 0; rg < 4; ++rg) rmin[mi][rg] = 1e30f;
#pragma unroll
    for (int mi = 0; mi < 4; ++mi) {
#pragma unroll
      for (int rg = 0; rg < 4; ++rg) {
        const int i = i0 + wm * 64 + mi * 16 + quad * 4 + rg;
        const float si = sq[i];
#pragma unroll
        for (int ni = 0; ni < 4; ++ni) {
          const float d2 = si + sqj[ni] - 2.f * acc[mi][ni][rg];
          const float dist = sqrtf(fmaxf(d2, 1e-12f));
          rmin[mi][rg] = fminf(rmin[mi][rg], dist);
          cmin[ni] = fminf(cmin[ni], dist);
        }
      }
    }
    // rows: reduce across lr lanes (masks 1,2,4,8)
#pragma unroll
    for (int m = 1; m < 16; m <<= 1)
#pragma unroll
      for (int mi = 0; mi < 4; ++mi)
#pragma unroll
        for (int rg = 0; rg < 4; ++rg)
          rmin[mi][rg] = fminf(rmin[mi][rg], __shfl_xor(rmin[mi][rg], m, 64));
    if (lr == 0) {
#pragma unroll
      for (int mi = 0; mi < 4; ++mi)
#pragma unroll
        for (int rg = 0; rg < 4; ++rg) {
          const int i = i0 + wm * 64 + mi * 16 + quad * 4 + rg;
          atomicMin(&an[i], __float_as_int(rmin[mi][rg]));
        }
    }
    // cols: reduce across quad groups (masks 16,32)
#pragma unroll
    for (int ni = 0; ni < 4; ++ni) {
      cmin[ni] = fminf(cmin[ni], __shfl_xor(cmin[ni], 16, 64));
      cmin[ni] = fminf(cmin[ni], __shfl_xor(cmin[ni], 32, 64));
    }
    if (quad == 0) {
#pragma unroll
      for (int ni = 0; ni < 4; ++ni) {
        const int j = j0 + wn * 64 + ni * 16 + lr;
        atomicMin(&an[j], __float_as_int(cmin[ni]));
      }
    }
  }
}

// ---------------- kernel 4: final combine ----------------
__global__ void final_kernel(const int* __restrict__ an, const int* __restrict__ ap,
                             const float* __restrict__ xloss, float* __restrict__ out) {
  const int tid = threadIdx.x;
  float st = 0.f, sx = 0.f;
  for (int i = tid; i < BATCH; i += 256) {
    const float a = __int_as_float(ap[i]);
    const float b = __int_as_float(an[i]);
    st += fmaxf(a - b + MARGIN, 0.f);
    sx += xloss[i];
  }
  st = wave_sum(st);
  sx = wave_sum(sx);
  __shared__ float s1[4], s2[4];
  if ((tid & 63) == 0) { s1[tid >> 6] = st; s2[tid >> 6] = sx; }
  __syncthreads();
  if (tid == 0) {
    const float trip = (s1[0] + s1[1] + s1[2] + s1[3]) / (float)BATCH;
    const float xent = (s2[0] + s2[1] + s2[2] + s2[3]) / (float)BATCH;
    out[0] = xent + trip;  // ALPHA=BETA=1
  }
}

// ---------------- launch ----------------
extern "C" void kernel_launch(void* const* d_in, const int* in_sizes, int n_in,
                              void* d_out, int out_size, void* d_ws, size_t ws_size,
                              hipStream_t stream) {
  const float* logits = (const float*)d_in[0];
  const float* feat   = (const float*)d_in[1];
  const int*   tgt    = (const int*)d_in[2];
  float* out = (float*)d_out;

  // ws layout: bf16 feat copy (16 MB) | sq | an | ap | xloss
  char* ws = (char*)d_ws;
  unsigned short* fb = (unsigned short*)ws;
  size_t off = (size_t)BATCH * FDIM * sizeof(unsigned short);
  float* sq    = (float*)(ws + off);  off += BATCH * sizeof(float);
  int*   an    = (int*)(ws + off);    off += BATCH * sizeof(int);
  int*   ap    = (int*)(ws + off);    off += BATCH * sizeof(int);
  float* xloss = (float*)(ws + off);

  const int NTILE = BATCH / TILE;                 // 32
  const int NTRI  = NTILE * (NTILE + 1) / 2;      // 528

  convert_init_kernel<<<BATCH, 256, 0, stream>>>(feat, fb, sq, an, ap);
  xent_kernel<<<BATCH, 256, 0, stream>>>(logits, tgt, xloss);
  gemm_mine_kernel<<<NTRI, 256, 0, stream>>>(fb, sq, an, ap);
  final_kernel<<<1, 256, 0, stream>>>(an, ap, xloss, out);
}

// Round 3
// 174.132 us; speedup vs baseline: 1.4373x; 1.0432x over previous
//
#include <hip/hip_runtime.h>
#include <hip/hip_bf16.h>

// Problem constants (from reference)
constexpr int BATCH = 4096;   // N
constexpr int NCLS  = 751;    // classes
constexpr int FDIM  = 2048;   // D
constexpr int TILE  = 128;    // C-tile (square)
constexpr int BK    = 32;     // K-step (one mfma_16x16x32 per step)
constexpr int NIT   = FDIM / BK;  // 64 K-iterations
constexpr float MARGIN = 0.5f;

constexpr int NTILE = BATCH / TILE;               // 32
constexpr int NOFF  = NTILE * (NTILE - 1) / 2;    // 496 strictly-lower tiles
constexpr int NGEMM = NOFF + NTILE;               // 528 (diag tiles LAST -> light tail)
constexpr int NXENT = 512;                        // xent blocks, 8 rows each

typedef __attribute__((ext_vector_type(8))) short bf16x8;  // 8 bf16 = 4 VGPRs
typedef __attribute__((ext_vector_type(4))) float f32x4;

// ---------------- helpers ----------------
__device__ __forceinline__ float wave_sum(float v) {
#pragma unroll
  for (int m = 32; m >= 1; m >>= 1) v += __shfl_xor(v, m, 64);
  return v;
}

__device__ __forceinline__ unsigned short bf_bits(float x) {
  unsigned u = __float_as_uint(x);
  u += 0x7FFFu + ((u >> 16) & 1u);   // RNE to bf16
  return (unsigned short)(u >> 16);
}

__device__ __forceinline__ void gld_lds16(const void* g, void* l) {
  __builtin_amdgcn_global_load_lds(
      (const __attribute__((address_space(1))) void*)g,
      (__attribute__((address_space(3))) void*)l, 16, 0, 0);
}

// ---------------- kernel 1: fp32->bf16 convert + row sum-of-squares + ws init ----
__global__ void convert_init_kernel(const float* __restrict__ feat,
                                    unsigned short* __restrict__ fb,
                                    float* __restrict__ sq,
                                    int* __restrict__ an, int* __restrict__ ap) {
  const int row = blockIdx.x;
  const int tid = threadIdx.x;
  const float4* src = (const float4*)(feat + (size_t)row * FDIM);
  ushort4* dst = (ushort4*)(fb + (size_t)row * FDIM);
  float s = 0.f;
#pragma unroll
  for (int it = 0; it < 2; ++it) {
    const int idx = it * 256 + tid;          // 512 float4 per row
    float4 v = src[idx];
    s += v.x * v.x + v.y * v.y + v.z * v.z + v.w * v.w;
    ushort4 o;
    o.x = bf_bits(v.x); o.y = bf_bits(v.y); o.z = bf_bits(v.z); o.w = bf_bits(v.w);
    dst[idx] = o;
  }
  s = wave_sum(s);
  __shared__ float ss[4];
  if ((tid & 63) == 0) ss[tid >> 6] = s;
  __syncthreads();
  if (tid == 0) {
    sq[row] = ss[0] + ss[1] + ss[2] + ss[3];
    an[row] = 0x7F000000;   // large positive float bits (min identity)
    ap[row] = 0;            // 0.0f bits (max identity; dist >= 0)
  }
}

// ---------------- kernel 2 (mega): heterogeneous blocks ----------------
// blocks [0, NGEMM): symmetric bf16 MFMA Gram tile + fused batch-hard mining,
//   double-buffered LDS prefetch. Off-diag tiles first, diag tiles last so the
//   16 "third-round" blocks on CUs 0-15 are the light (half-staging) ones.
// blocks [NGEMM, NGEMM+NXENT): cross-entropy, 8 rows per block (1 row/wave x2).
__global__ __launch_bounds__(256) void mega_kernel(
    const unsigned short* __restrict__ fb, const float* __restrict__ sq,
    int* __restrict__ an, int* __restrict__ ap,
    const float* __restrict__ logits, const int* __restrict__ tgt,
    float* __restrict__ xloss) {
  const int b = blockIdx.x;
  const int tid = threadIdx.x;
  const int wave = tid >> 6, lane = tid & 63;

  if (b >= NGEMM) {
    // ---------------- cross-entropy part ----------------
    const int r0 = (b - NGEMM) * 8;
#pragma unroll
    for (int rr = 0; rr < 2; ++rr) {
      const int row = r0 + rr * 4 + wave;
      const float* lg = logits + (size_t)row * NCLS;
      float m = -1e30f;
      for (int j = lane; j < NCLS; j += 64) m = fmaxf(m, lg[j]);
#pragma unroll
      for (int s = 32; s >= 1; s >>= 1) m = fmaxf(m, __shfl_xor(m, s, 64));
      float se = 0.f;
      for (int j = lane; j < NCLS; j += 64) se += __expf(lg[j] - m);
      se = wave_sum(se);
      if (lane == 0) xloss[row] = -(lg[tgt[row]] - m - logf(se));
    }
    return;
  }

  // ---------------- GEMM + mining part ----------------
  __shared__ __align__(16) unsigned short As[2][TILE * BK];  // 2 x 8 KB
  __shared__ __align__(16) unsigned short Bs[2][TILE * BK];  // 2 x 8 KB

  int bi, bj;
  bool diag;
  if (b < NOFF) {
    // strictly-lower triangle: b = bi*(bi-1)/2 + bj, bj < bi
    bi = (int)((1.f + sqrtf(8.f * (float)b + 1.f)) * 0.5f);
    while (bi * (bi - 1) / 2 > b) --bi;
    while ((bi + 1) * bi / 2 <= b) ++bi;
    bj = b - bi * (bi - 1) / 2;
    diag = false;
  } else {
    bi = bj = b - NOFF;
    diag = true;
  }

  const int i0 = bi * TILE, j0 = bj * TILE;
  const int wm = wave >> 1, wn = wave & 1;        // 2x2 wave grid
  const int quad = lane >> 4, lr = lane & 15;

  f32x4 acc[4][4];
  const f32x4 zero = {0.f, 0.f, 0.f, 0.f};
#pragma unroll
  for (int mi = 0; mi < 4; ++mi)
#pragma unroll
    for (int ni = 0; ni < 4; ++ni) acc[mi][ni] = zero;

  // staging map: thread t -> LDS byte offset t*16 (wave-uniform base + lane*16,
  // required by global_load_lds). Covers rows 0..63; second load rows 64..127.
  const int r = tid >> 2;          // 0..63
  const int c = (tid & 3) * 8;     // 0,8,16,24
  const unsigned short* gA = fb + (size_t)(i0 + r) * FDIM + c;
  const unsigned short* gB = fb + (size_t)(j0 + r) * FDIM + c;
  const int lo = r * BK + c;       // element offset in one buffer

  // prefetch iteration 0 into buffer 0
  gld_lds16(gA, &As[0][lo]);
  gld_lds16(gA + (size_t)64 * FDIM, &As[0][lo + 64 * BK]);
  if (!diag) {
    gld_lds16(gB, &Bs[0][lo]);
    gld_lds16(gB + (size_t)64 * FDIM, &Bs[0][lo + 64 * BK]);
  }

  for (int it = 0; it < NIT; ++it) {
    const int cur = it & 1;
    __syncthreads();   // drains vmcnt -> buffer `cur` (prefetched last iter) visible
    if (it + 1 < NIT) {
      const int nk = (it + 1) * BK;
      const int nb = cur ^ 1;
      gld_lds16(gA + nk, &As[nb][lo]);
      gld_lds16(gA + nk + (size_t)64 * FDIM, &As[nb][lo + 64 * BK]);
      if (!diag) {
        gld_lds16(gB + nk, &Bs[nb][lo]);
        gld_lds16(gB + nk + (size_t)64 * FDIM, &Bs[nb][lo + 64 * BK]);
      }
    }
    const unsigned short* Asb = As[cur];
    const unsigned short* Bsb = diag ? As[cur] : Bs[cur];

    bf16x8 a[4], bfr[4];
#pragma unroll
    for (int mi = 0; mi < 4; ++mi)
      a[mi] = *(const bf16x8*)&Asb[(wm * 64 + mi * 16 + lr) * BK + quad * 8];
#pragma unroll
    for (int ni = 0; ni < 4; ++ni)
      bfr[ni] = *(const bf16x8*)&Bsb[(wn * 64 + ni * 16 + lr) * BK + quad * 8];
#pragma unroll
    for (int mi = 0; mi < 4; ++mi)
#pragma unroll
      for (int ni = 0; ni < 4; ++ni)
        acc[mi][ni] = __builtin_amdgcn_mfma_f32_16x16x32_bf16(
            a[mi], bfr[ni], acc[mi][ni], 0, 0, 0);
  }

  // ---- epilogue: D layout col = lane&15 (j), row = quad*4 + reg (i) ----
  float sqj[4];
#pragma unroll
  for (int ni = 0; ni < 4; ++ni) sqj[ni] = sq[j0 + wn * 64 + ni * 16 + lr];

  if (diag) {
    // same-group pairs live only here; tile symmetric -> row mining suffices
    float rmin[4][4], rmax[4][4];
#pragma unroll
    for (int mi = 0; mi < 4; ++mi)
#pragma unroll
      for (int rg = 0; rg < 4; ++rg) { rmin[mi][rg] = 1e30f; rmax[mi][rg] = 0.f; }
#pragma unroll
    for (int mi = 0; mi < 4; ++mi) {
#pragma unroll
      for (int rg = 0; rg < 4; ++rg) {
        const int i = i0 + wm * 64 + mi * 16 + quad * 4 + rg;
        const float si = sq[i];
        const int gi = i >> 2;       // targets = idx // 4
#pragma unroll
        for (int ni = 0; ni < 4; ++ni) {
          const int j = j0 + wn * 64 + ni * 16 + lr;
          const float d2 = si + sqj[ni] - 2.f * acc[mi][ni][rg];
          const float dist = sqrtf(fmaxf(d2, 1e-12f));
          if ((j >> 2) == gi) rmax[mi][rg] = fmaxf(rmax[mi][rg], dist);
          else                rmin[mi][rg] = fminf(rmin[mi][rg], dist);
        }
      }
    }
#pragma unroll
    for (int m = 1; m < 16; m <<= 1)
#pragma unroll
      for (int mi = 0; mi < 4; ++mi)
#pragma unroll
        for (int rg = 0; rg < 4; ++rg) {
          rmin[mi][rg] = fminf(rmin[mi][rg], __shfl_xor(rmin[mi][rg], m, 64));
          rmax[mi][rg] = fmaxf(rmax[mi][rg], __shfl_xor(rmax[mi][rg], m, 64));
        }
    if (lr == 0) {
#pragma unroll
      for (int mi = 0; mi < 4; ++mi)
#pragma unroll
        for (int rg = 0; rg < 4; ++rg) {
          const int i = i0 + wm * 64 + mi * 16 + quad * 4 + rg;
          atomicMin(&an[i], __float_as_int(rmin[mi][rg]));
          atomicMax(&ap[i], __float_as_int(rmax[mi][rg]));
        }
    }
  } else {
    // all cross-group: row-min -> an[i], col-min (symmetry) -> an[j]
    float rmin[4][4];
    float cmin[4] = {1e30f, 1e30f, 1e30f, 1e30f};
#pragma unroll
    for (int mi = 0; mi < 4; ++mi)
#pragma unroll
      for (int rg = 0; rg < 4; ++rg) rmin[mi][rg] = 1e30f;
#pragma unroll
    for (int mi = 0; mi < 4; ++mi) {
#pragma unroll
      for (int rg = 0; rg < 4; ++rg) {
        const float si = sq[i0 + wm * 64 + mi * 16 + quad * 4 + rg];
#pragma unroll
        for (int ni = 0; ni < 4; ++ni) {
          const float d2 = si + sqj[ni] - 2.f * acc[mi][ni][rg];
          const float dist = sqrtf(fmaxf(d2, 1e-12f));
          rmin[mi][rg] = fminf(rmin[mi][rg], dist);
          cmin[ni] = fminf(cmin[ni], dist);
        }
      }
    }
    // rows: reduce across lr lanes (masks 1,2,4,8)
#pragma unroll
    for (int m = 1; m < 16; m <<= 1)
#pragma unroll
      for (int mi = 0; mi < 4; ++mi)
#pragma unroll
        for (int rg = 0; rg < 4; ++rg)
          rmin[mi][rg] = fminf(rmin[mi][rg], __shfl_xor(rmin[mi][rg], m, 64));
    if (lr == 0) {
#pragma unroll
      for (int mi = 0; mi < 4; ++mi)
#pragma unroll
        for (int rg = 0; rg < 4; ++rg) {
          const int i = i0 + wm * 64 + mi * 16 + quad * 4 + rg;
          atomicMin(&an[i], __float_as_int(rmin[mi][rg]));
        }
    }
    // cols: reduce across quad groups (masks 16,32)
#pragma unroll
    for (int ni = 0; ni < 4; ++ni) {
      cmin[ni] = fminf(cmin[ni], __shfl_xor(cmin[ni], 16, 64));
      cmin[ni] = fminf(cmin[ni], __shfl_xor(cmin[ni], 32, 64));
    }
    if (quad == 0) {
#pragma unroll
      for (int ni = 0; ni < 4; ++ni) {
        const int j = j0 + wn * 64 + ni * 16 + lr;
        atomicMin(&an[j], __float_as_int(cmin[ni]));
      }
    }
  }
}

// ---------------- kernel 3: final combine ----------------
__global__ void final_kernel(const int* __restrict__ an, const int* __restrict__ ap,
                             const float* __restrict__ xloss, float* __restrict__ out) {
  const int tid = threadIdx.x;
  float st = 0.f, sx = 0.f;
  for (int i = tid; i < BATCH; i += 256) {
    const float a = __int_as_float(ap[i]);
    const float b = __int_as_float(an[i]);
    st += fmaxf(a - b + MARGIN, 0.f);
    sx += xloss[i];
  }
  st = wave_sum(st);
  sx = wave_sum(sx);
  __shared__ float s1[4], s2[4];
  if ((tid & 63) == 0) { s1[tid >> 6] = st; s2[tid >> 6] = sx; }
  __syncthreads();
  if (tid == 0) {
    const float trip = (s1[0] + s1[1] + s1[2] + s1[3]) / (float)BATCH;
    const float xent = (s2[0] + s2[1] + s2[2] + s2[3]) / (float)BATCH;
    out[0] = xent + trip;  // ALPHA=BETA=1
  }
}

// ---------------- launch ----------------
extern "C" void kernel_launch(void* const* d_in, const int* in_sizes, int n_in,
                              void* d_out, int out_size, void* d_ws, size_t ws_size,
                              hipStream_t stream) {
  const float* logits = (const float*)d_in[0];
  const float* feat   = (const float*)d_in[1];
  const int*   tgt    = (const int*)d_in[2];
  float* out = (float*)d_out;

  // ws layout: bf16 feat copy (16 MB) | sq | an | ap | xloss
  char* ws = (char*)d_ws;
  unsigned short* fb = (unsigned short*)ws;
  size_t off = (size_t)BATCH * FDIM * sizeof(unsigned short);
  float* sq    = (float*)(ws + off);  off += BATCH * sizeof(float);
  int*   an    = (int*)(ws + off);    off += BATCH * sizeof(int);
  int*   ap    = (int*)(ws + off);    off += BATCH * sizeof(int);
  float* xloss = (float*)(ws + off);

  convert_init_kernel<<<BATCH, 256, 0, stream>>>(feat, fb, sq, an, ap);
  mega_kernel<<<NGEMM + NXENT, 256, 0, stream>>>(fb, sq, an, ap, logits, tgt, xloss);
  final_kernel<<<1, 256, 0, stream>>>(an, ap, xloss, out);
}